// Round 8
// baseline (89.671 us; speedup 1.0000x reference)
//
#include <hip/hip_runtime.h>

// BoundaryAwareLoss = dice(pred,target) + bce(sigmoid(pred)*boundary, target*boundary)
// boundary = 15x15 (dilate - erode) of binary target, clipped windows == clamp-to-edge.
// BCE broadcast (B,B,H,W) factors per pixel:
//   sum_{b1,b2} bd[b1,px]*f[b2,px] = cnt(px)*F(px); bd==0 pixels contribute 0.
//   (absmax 0.0 verified rounds 1,3,4,5,6)
// target binary -> bit-pack via __ballot during the single 19 MB float stream (K1);
// dilate/erode are bitwise OR/AND stencils on packed words (K2, all-L2):
//   vertical = OR/AND over 15 clamped rows; horizontal = u64 shift chains with
//   zeros-for-OR / ones-for-AND edge substitution (clipped window).
// K2 fuses the final reduction via last-block ticket. 3 dispatches total.
//
// bp layout: bp[wordpos*8 + b], wordpos = y*17 + xu (544 = 17*32 exactly),
// bit j of word = pixel y*544 + xu*32 + j.

#define BB   8
#define HH   544
#define WW   544
#define HWS  (HH * WW)          // 295936
#define WPR  (WW / 32)          // 17 words per row
#define NWP  (HH * WPR)         // 9248 word positions
#define KK   15
#define PADR 7
#define NB1  (HWS / 256)        // 1156 K1 blocks (exact)
#define NB2  (NWP * BB / 256)   // 289 K2 blocks (exact)

// ---- K1: stream pred+targ once; ballot-pack target bits; F = sum_b f; dice ----
__global__ __launch_bounds__(256) void ba_k1(
    const float* __restrict__ pred, const float* __restrict__ targ,
    unsigned int* __restrict__ bp, float* __restrict__ Farr,
    float4* __restrict__ part1)
{
    __shared__ float red[4][3];
    const int px   = blockIdx.x * 256 + threadIdx.x;   // exact, no tail
    const int lane = threadIdx.x & 63;
    const int w0   = px >> 5;                          // this lane's word position

    float sp = 0.f, st = 0.f, si = 0.f, F = 0.f;
    #pragma unroll
    for (int b = 0; b < BB; ++b) {
        float t = targ[(size_t)b * HWS + px];
        float p = pred[(size_t)b * HWS + px];
        unsigned long long m = __ballot(t > 0.5f);     // 64 px = 2 words
        if (lane == 0)  bp[w0 * 8 + b] = (unsigned int)m;
        if (lane == 32) bp[w0 * 8 + b] = (unsigned int)(m >> 32); // lane32: w0 = base+1
        sp += p; st += t; si += p * t;
        // f = t*max(log(sig p),-100) + (1-t)*max(log(1-sig p),-100), stable softplus
        float a   = __logf(1.f + __expf(-fabsf(p)));
        float lp  = fmaxf(-(fmaxf(-p, 0.f) + a), -100.f);
        float l1p = fmaxf(-(fmaxf( p, 0.f) + a), -100.f);
        F += l1p + t * (lp - l1p);
    }
    Farr[px] = F;

    #pragma unroll
    for (int off = 32; off > 0; off >>= 1) {
        sp += __shfl_down(sp, off);
        st += __shfl_down(st, off);
        si += __shfl_down(si, off);
    }
    int wave = threadIdx.x >> 6;
    if (lane == 0) { red[wave][0] = sp; red[wave][1] = st; red[wave][2] = si; }
    __syncthreads();
    if (threadIdx.x == 0) {
        float a0 = 0.f, a1 = 0.f, a2 = 0.f;
        #pragma unroll
        for (int w = 0; w < 4; ++w) { a0 += red[w][0]; a1 += red[w][1]; a2 += red[w][2]; }
        part1[blockIdx.x] = make_float4(a0, a1, a2, 0.f);
    }
}

// ---- K2: bit stencil (v then h) + cnt*F + fused last-block finalize ----
__global__ __launch_bounds__(256) void ba_k2(
    const unsigned int* __restrict__ bp, const float* __restrict__ Farr,
    const float4* __restrict__ part1, float* __restrict__ part2,
    unsigned int* __restrict__ ticket, float* __restrict__ out)
{
    __shared__ unsigned int bdsh[256];
    __shared__ float red[4];
    __shared__ int lastblk;
    const int tid = threadIdx.x;
    const int idx = blockIdx.x * 256 + tid;        // = wp*8 + b
    const int b   = idx & 7;
    const int wp  = idx >> 3;                      // word position, 0..9247
    const int y   = wp / WPR, xu = wp - y * WPR;

    // vertical 15-tap (clamped rows) on raw words, for xu-1, xu, xu+1
    unsigned int vorL = 0u, vanL = 0xFFFFFFFFu;
    unsigned int vorC = 0u, vanC = 0xFFFFFFFFu;
    unsigned int vorR = 0u, vanR = 0xFFFFFFFFu;
    #pragma unroll
    for (int j = 0; j < KK; ++j) {
        int yy = y - PADR + j; yy = yy < 0 ? 0 : (yy > HH - 1 ? HH - 1 : yy);
        int rb = (yy * WPR + xu) * 8 + b;
        unsigned int wc = bp[rb];
        vorC |= wc; vanC &= wc;
        if (xu > 0)       { unsigned int wl = bp[rb - 8];  vorL |= wl; vanL &= wl; }
        if (xu < WPR - 1) { unsigned int wr = bp[rb + 8];  vorR |= wr; vanR &= wr; }
    }
    if (xu == 0)       { vorL = 0u; vanL = 0xFFFFFFFFu; }   // clipped window edges
    if (xu == WPR - 1) { vorR = 0u; vanR = 0xFFFFFFFFu; }

    // horizontal 15-tap via u64 shift chains
    unsigned long long Ao = ((unsigned long long)vorC << 32) | vorL;
    unsigned long long Bo = ((unsigned long long)vorR << 32) | vorC;
    unsigned long long Aa = ((unsigned long long)vanC << 32) | vanL;
    unsigned long long Ba = ((unsigned long long)vanR << 32) | vanC;
    unsigned int hOR = vorC, hAND = vanC;
    #pragma unroll
    for (int s = 1; s <= PADR; ++s) {
        hOR  |= (unsigned int)(Ao >> (32 - s)) | (unsigned int)(Bo >> s);
        hAND &= (unsigned int)(Aa >> (32 - s)) & (unsigned int)(Ba >> s);
    }
    bdsh[tid] = hOR & ~hAND;                       // boundary bits, 32 px
    __syncthreads();

    // cnt*F: thread handles 4 px of word slot (tid>>3), group (tid&7)
    const int wslot = tid >> 3, sub = tid & 7;
    const int gpx = (blockIdx.x * 32 + wslot) * 32 + sub * 4;
    const float4 Fv = *(const float4*)(Farr + gpx);
    unsigned int w0 = bdsh[wslot * 8 + 0], w1 = bdsh[wslot * 8 + 1];
    unsigned int w2 = bdsh[wslot * 8 + 2], w3 = bdsh[wslot * 8 + 3];
    unsigned int w4 = bdsh[wslot * 8 + 4], w5 = bdsh[wslot * 8 + 5];
    unsigned int w6 = bdsh[wslot * 8 + 6], w7 = bdsh[wslot * 8 + 7];
    float bs = 0.f;
    const float* Fp = (const float*)&Fv;
    #pragma unroll
    for (int k = 0; k < 4; ++k) {
        int p = sub * 4 + k;
        unsigned int cnt = ((w0 >> p) & 1u) + ((w1 >> p) & 1u)
                         + ((w2 >> p) & 1u) + ((w3 >> p) & 1u)
                         + ((w4 >> p) & 1u) + ((w5 >> p) & 1u)
                         + ((w6 >> p) & 1u) + ((w7 >> p) & 1u);
        bs += (float)cnt * Fp[k];
    }

    #pragma unroll
    for (int off = 32; off > 0; off >>= 1) bs += __shfl_down(bs, off);
    int wave = tid >> 6, lane = tid & 63;
    if (lane == 0) red[wave] = bs;
    __syncthreads();
    if (tid == 0) {
        part2[blockIdx.x] = red[0] + red[1] + red[2] + red[3];
        __threadfence();                           // release partial before ticket
        unsigned int old = atomicAdd(ticket, 1u);
        lastblk = (old == NB2 - 1);
    }
    __syncthreads();

    if (lastblk) {                                 // exactly one block: finalize
        __threadfence();                           // acquire all partials
        float sp = 0.f, st = 0.f, si = 0.f, b2 = 0.f;
        for (int i = tid; i < NB1; i += 256) {
            float4 v = part1[i];
            sp += v.x; st += v.y; si += v.z;
        }
        for (int i = tid; i < NB2; i += 256) b2 += part2[i];
        #pragma unroll
        for (int off = 32; off > 0; off >>= 1) {
            sp += __shfl_down(sp, off);
            st += __shfl_down(st, off);
            si += __shfl_down(si, off);
            b2 += __shfl_down(b2, off);
        }
        __syncthreads();                           // bdsh reuse safety
        __shared__ float r2[4][4];
        if (lane == 0) { r2[wave][0] = sp; r2[wave][1] = st; r2[wave][2] = si; r2[wave][3] = b2; }
        __syncthreads();
        if (tid == 0) {
            float a0 = 0.f, a1 = 0.f, a2 = 0.f, a3 = 0.f;
            #pragma unroll
            for (int w = 0; w < 4; ++w) {
                a0 += r2[w][0]; a1 += r2[w][1]; a2 += r2[w][2]; a3 += r2[w][3];
            }
            float dice = 1.f - (2.f * a2 + 1.f) / (a0 + a1 + 1.f);
            float bce  = -a3 / (float)((long long)BB * BB * HH * WW);
            out[0] = dice + bce;
        }
    }
}

extern "C" void kernel_launch(void* const* d_in, const int* in_sizes, int n_in,
                              void* d_out, int out_size, void* d_ws, size_t ws_size,
                              hipStream_t stream) {
    const float* pred = (const float*)d_in[0];
    const float* targ = (const float*)d_in[1];
    float* out = (float*)d_out;

    char* w = (char*)d_ws;
    unsigned int* bp     = (unsigned int*)w;                       // 295936 B
    float*        Farr   = (float*)(w + 295936);                   // 1183744 B
    float4*       part1  = (float4*)(w + 295936 + 1183744);        // 18496 B
    float*        part2  = (float*)(w + 295936 + 1183744 + 18496); // 1156 B
    unsigned int* ticket = (unsigned int*)(w + 295936 + 1183744 + 18496 + 1156);

    hipMemsetAsync(ticket, 0, 4, stream);
    ba_k1<<<NB1, 256, 0, stream>>>(pred, targ, bp, Farr, part1);
    ba_k2<<<NB2, 256, 0, stream>>>(bp, Farr, part1, part2, ticket, out);
}

// Round 9
// 81.694 us; speedup vs baseline: 1.0976x; 1.0976x over previous
//
#include <hip/hip_runtime.h>

// BoundaryAwareLoss = dice(pred,target) + bce(sigmoid(pred)*boundary, target*boundary)
// boundary = 15x15 (dilate - erode) of binary target, clipped windows == clamp-to-edge.
// BCE broadcast (B,B,H,W) factors per pixel:
//   sum_{b1,b2} bd[b1,px]*f[b2,px] = cnt(px)*F(px); bd==0 pixels contribute 0.
//   (absmax 0.0 verified rounds 1,3,4,5,6,8)
// target binary -> bit-pack via __ballot during the single 19 MB float stream (K1);
// dilate/erode are bitwise OR/AND stencils on packed words (K2, all-L2/L3):
//   vertical = OR/AND over 15 clamped rows; horizontal = u64 shift chains with
//   zeros-for-OR / ones-for-AND edge substitution (clipped window).
// NO device-scope sync: R8's ticket+threadfence finalize cost ~10 us (289 block
// release-fences + acquire across 8 non-coherent XCDs). Plain 3-dispatch
// pipeline instead: K1 -> K2 -> 1-block final. No atomics, no memset.
//
// bp layout: bp[wordpos*8 + b], wordpos = y*17 + xu (544 = 17*32 exactly),
// bit j of word = pixel y*544 + xu*32 + j.

#define BB   8
#define HH   544
#define WW   544
#define HWS  (HH * WW)          // 295936
#define WPR  (WW / 32)          // 17 words per row
#define NWP  (HH * WPR)         // 9248 word positions
#define KK   15
#define PADR 7
#define NB1  (HWS / 256)        // 1156 K1 blocks (exact)
#define NB2  (NWP * BB / 256)   // 289 K2 blocks (exact)

// ---- K1: stream pred+targ once; ballot-pack target bits; F = sum_b f; dice ----
__global__ __launch_bounds__(256) void ba_k1(
    const float* __restrict__ pred, const float* __restrict__ targ,
    unsigned int* __restrict__ bp, float* __restrict__ Farr,
    float4* __restrict__ part1)
{
    __shared__ float red[4][3];
    const int px   = blockIdx.x * 256 + threadIdx.x;   // exact, no tail
    const int lane = threadIdx.x & 63;
    const int w0   = px >> 5;                          // this lane's word position

    float sp = 0.f, st = 0.f, si = 0.f, F = 0.f;
    #pragma unroll
    for (int b = 0; b < BB; ++b) {
        float t = targ[(size_t)b * HWS + px];
        float p = pred[(size_t)b * HWS + px];
        unsigned long long m = __ballot(t > 0.5f);     // 64 px = 2 words
        if (lane == 0)  bp[w0 * 8 + b] = (unsigned int)m;
        if (lane == 32) bp[w0 * 8 + b] = (unsigned int)(m >> 32); // lane32: w0 = base+1
        sp += p; st += t; si += p * t;
        // f = t*max(log(sig p),-100) + (1-t)*max(log(1-sig p),-100), stable softplus
        float a   = __logf(1.f + __expf(-fabsf(p)));
        float lp  = fmaxf(-(fmaxf(-p, 0.f) + a), -100.f);
        float l1p = fmaxf(-(fmaxf( p, 0.f) + a), -100.f);
        F += l1p + t * (lp - l1p);
    }
    Farr[px] = F;

    #pragma unroll
    for (int off = 32; off > 0; off >>= 1) {
        sp += __shfl_down(sp, off);
        st += __shfl_down(st, off);
        si += __shfl_down(si, off);
    }
    int wave = threadIdx.x >> 6;
    if (lane == 0) { red[wave][0] = sp; red[wave][1] = st; red[wave][2] = si; }
    __syncthreads();
    if (threadIdx.x == 0) {
        float a0 = 0.f, a1 = 0.f, a2 = 0.f;
        #pragma unroll
        for (int w = 0; w < 4; ++w) { a0 += red[w][0]; a1 += red[w][1]; a2 += red[w][2]; }
        part1[blockIdx.x] = make_float4(a0, a1, a2, 0.f);
    }
}

// ---- K2: bit stencil (v then h) + cnt*F partials (no atomics, no fences) ----
__global__ __launch_bounds__(256) void ba_k2(
    const unsigned int* __restrict__ bp, const float* __restrict__ Farr,
    float* __restrict__ part2)
{
    __shared__ unsigned int bdsh[256];
    __shared__ float red[4];
    const int tid = threadIdx.x;
    const int idx = blockIdx.x * 256 + tid;        // = wp*8 + b
    const int b   = idx & 7;
    const int wp  = idx >> 3;                      // word position, 0..9247
    const int y   = wp / WPR, xu = wp - y * WPR;

    // vertical 15-tap (clamped rows) on raw words, for xu-1, xu, xu+1
    unsigned int vorL = 0u, vanL = 0xFFFFFFFFu;
    unsigned int vorC = 0u, vanC = 0xFFFFFFFFu;
    unsigned int vorR = 0u, vanR = 0xFFFFFFFFu;
    #pragma unroll
    for (int j = 0; j < KK; ++j) {
        int yy = y - PADR + j; yy = yy < 0 ? 0 : (yy > HH - 1 ? HH - 1 : yy);
        int rb = (yy * WPR + xu) * 8 + b;
        unsigned int wc = bp[rb];
        vorC |= wc; vanC &= wc;
        if (xu > 0)       { unsigned int wl = bp[rb - 8];  vorL |= wl; vanL &= wl; }
        if (xu < WPR - 1) { unsigned int wr = bp[rb + 8];  vorR |= wr; vanR &= wr; }
    }
    if (xu == 0)       { vorL = 0u; vanL = 0xFFFFFFFFu; }   // clipped window edges
    if (xu == WPR - 1) { vorR = 0u; vanR = 0xFFFFFFFFu; }

    // horizontal 15-tap via u64 shift chains
    unsigned long long Ao = ((unsigned long long)vorC << 32) | vorL;
    unsigned long long Bo = ((unsigned long long)vorR << 32) | vorC;
    unsigned long long Aa = ((unsigned long long)vanC << 32) | vanL;
    unsigned long long Ba = ((unsigned long long)vanR << 32) | vanC;
    unsigned int hOR = vorC, hAND = vanC;
    #pragma unroll
    for (int s = 1; s <= PADR; ++s) {
        hOR  |= (unsigned int)(Ao >> (32 - s)) | (unsigned int)(Bo >> s);
        hAND &= (unsigned int)(Aa >> (32 - s)) & (unsigned int)(Ba >> s);
    }
    bdsh[tid] = hOR & ~hAND;                       // boundary bits, 32 px
    __syncthreads();

    // cnt*F: thread handles 4 px of word slot (tid>>3), group (tid&7)
    const int wslot = tid >> 3, sub = tid & 7;
    const int gpx = (blockIdx.x * 32 + wslot) * 32 + sub * 4;
    const float4 Fv = *(const float4*)(Farr + gpx);
    unsigned int w0 = bdsh[wslot * 8 + 0], w1 = bdsh[wslot * 8 + 1];
    unsigned int w2 = bdsh[wslot * 8 + 2], w3 = bdsh[wslot * 8 + 3];
    unsigned int w4 = bdsh[wslot * 8 + 4], w5 = bdsh[wslot * 8 + 5];
    unsigned int w6 = bdsh[wslot * 8 + 6], w7 = bdsh[wslot * 8 + 7];
    float bs = 0.f;
    const float* Fp = (const float*)&Fv;
    #pragma unroll
    for (int k = 0; k < 4; ++k) {
        int p = sub * 4 + k;
        unsigned int cnt = ((w0 >> p) & 1u) + ((w1 >> p) & 1u)
                         + ((w2 >> p) & 1u) + ((w3 >> p) & 1u)
                         + ((w4 >> p) & 1u) + ((w5 >> p) & 1u)
                         + ((w6 >> p) & 1u) + ((w7 >> p) & 1u);
        bs += (float)cnt * Fp[k];
    }

    #pragma unroll
    for (int off = 32; off > 0; off >>= 1) bs += __shfl_down(bs, off);
    int wave = tid >> 6, lane = tid & 63;
    if (lane == 0) red[wave] = bs;
    __syncthreads();
    if (tid == 0)
        part2[blockIdx.x] = red[0] + red[1] + red[2] + red[3];
}

// ---- final: sum partials, compose loss ----
__global__ __launch_bounds__(256) void ba_final(
    const float4* __restrict__ part1, const float* __restrict__ part2,
    float* __restrict__ out)
{
    __shared__ float red[4][4];
    float sp = 0.f, st = 0.f, si = 0.f, bs = 0.f;
    for (int i = threadIdx.x; i < NB1; i += 256) {
        float4 v = part1[i];
        sp += v.x; st += v.y; si += v.z;
    }
    for (int i = threadIdx.x; i < NB2; i += 256) bs += part2[i];
    #pragma unroll
    for (int off = 32; off > 0; off >>= 1) {
        sp += __shfl_down(sp, off);
        st += __shfl_down(st, off);
        si += __shfl_down(si, off);
        bs += __shfl_down(bs, off);
    }
    int wave = threadIdx.x >> 6, lane = threadIdx.x & 63;
    if (lane == 0) {
        red[wave][0] = sp; red[wave][1] = st; red[wave][2] = si; red[wave][3] = bs;
    }
    __syncthreads();
    if (threadIdx.x == 0) {
        float a0 = 0.f, a1 = 0.f, a2 = 0.f, a3 = 0.f;
        #pragma unroll
        for (int w = 0; w < 4; ++w) {
            a0 += red[w][0]; a1 += red[w][1]; a2 += red[w][2]; a3 += red[w][3];
        }
        float dice = 1.f - (2.f * a2 + 1.f) / (a0 + a1 + 1.f);
        float bce  = -a3 / (float)((long long)BB * BB * HH * WW);
        out[0] = dice + bce;
    }
}

extern "C" void kernel_launch(void* const* d_in, const int* in_sizes, int n_in,
                              void* d_out, int out_size, void* d_ws, size_t ws_size,
                              hipStream_t stream) {
    const float* pred = (const float*)d_in[0];
    const float* targ = (const float*)d_in[1];
    float* out = (float*)d_out;

    char* w = (char*)d_ws;
    unsigned int* bp    = (unsigned int*)w;                       // 295936 B
    float*        Farr  = (float*)(w + 295936);                   // 1183744 B
    float4*       part1 = (float4*)(w + 295936 + 1183744);        // 18496 B
    float*        part2 = (float*)(w + 295936 + 1183744 + 18496); // 1156 B

    ba_k1<<<NB1, 256, 0, stream>>>(pred, targ, bp, Farr, part1);
    ba_k2<<<NB2, 256, 0, stream>>>(bp, Farr, part2);
    ba_final<<<1, 256, 0, stream>>>(part1, part2, out);
}

// Round 10
// 80.668 us; speedup vs baseline: 1.1116x; 1.0127x over previous
//
#include <hip/hip_runtime.h>

// BoundaryAwareLoss = dice(pred,target) + bce(sigmoid(pred)*boundary, target*boundary)
// boundary = 15x15 (dilate - erode) of binary target, clipped windows == clamp-to-edge.
// BCE broadcast (B,B,H,W) factors per pixel:
//   sum_{b1,b2} bd[b1,px]*f[b2,px] = cnt(px)*F(px); bd==0 pixels contribute 0.
//   (absmax 0.0 verified rounds 1,3,4,5,6,8,9)
// target binary -> bit-packed words; dilate/erode = OR/AND bit stencils (K2, all-L2):
//   vertical = OR/AND over 15 clamped rows; horizontal = u64 shift chains with
//   zeros-for-OR / ones-for-AND edge substitution (clipped window).
// K1 float4-vectorized (G13): 4 px/thread, 16x16B loads, LDS nibble-pack for bits.
// NO device-scope sync (R8 lesson: ticket+threadfence finalize cost ~8-10 us on
// 8 non-coherent XCDs). Plain 3-dispatch pipeline: K1 -> K2 -> 1-block final.
//
// bp layout: bp[wordpos*8 + b], wordpos = y*17 + xu (544 = 17*32 exactly),
// bit j of word = pixel y*544 + xu*32 + j.

#define BB   8
#define HH   544
#define WW   544
#define HWS  (HH * WW)          // 295936
#define WPR  (WW / 32)          // 17 words per row
#define NWP  (HH * WPR)         // 9248 word positions
#define KK   15
#define PADR 7
#define NB1  (HWS / 1024)       // 289 K1 blocks (4 px/thread, exact)
#define NB2  (NWP * BB / 256)   // 289 K2 blocks (exact)

// ---- K1: float4 stream of pred+targ; LDS nibble-pack bits; F quad; dice ----
__global__ __launch_bounds__(256) void ba_k1(
    const float* __restrict__ pred, const float* __restrict__ targ,
    unsigned int* __restrict__ bp, float4* __restrict__ Farr,
    float4* __restrict__ part1)
{
    __shared__ unsigned int nib[256];
    __shared__ float red[4][3];
    const int tid = threadIdx.x;
    const int q   = blockIdx.x * 256 + tid;        // pixel-quad index, exact
    const size_t px4 = (size_t)q * 4;

    float sp = 0.f, st = 0.f, si = 0.f;
    float F0 = 0.f, F1 = 0.f, F2 = 0.f, F3 = 0.f;
    unsigned int nibAll = 0u;                      // 4 bits/plane x 8 planes

    #pragma unroll
    for (int b = 0; b < BB; ++b) {
        const float4 t = *(const float4*)(targ + (size_t)b * HWS + px4);
        const float4 p = *(const float4*)(pred + (size_t)b * HWS + px4);
        unsigned int nb = (t.x > 0.5f ? 1u : 0u)
                        | (t.y > 0.5f ? 2u : 0u)
                        | (t.z > 0.5f ? 4u : 0u)
                        | (t.w > 0.5f ? 8u : 0u);
        nibAll |= nb << (b * 4);
        sp += p.x + p.y + p.z + p.w;
        st += t.x + t.y + t.z + t.w;
        si += p.x * t.x + p.y * t.y + p.z * t.z + p.w * t.w;
        // f = t*max(log(sig p),-100) + (1-t)*max(log(1-sig p),-100), stable softplus
        #define FTERM(pp, tt, acc) { \
            float a_   = __logf(1.f + __expf(-fabsf(pp)));      \
            float lp_  = fmaxf(-(fmaxf(-(pp), 0.f) + a_), -100.f); \
            float l1p_ = fmaxf(-(fmaxf( (pp), 0.f) + a_), -100.f); \
            acc += l1p_ + (tt) * (lp_ - l1p_); }
        FTERM(p.x, t.x, F0)
        FTERM(p.y, t.y, F1)
        FTERM(p.z, t.z, F2)
        FTERM(p.w, t.w, F3)
        #undef FTERM
    }
    Farr[q] = make_float4(F0, F1, F2, F3);
    nib[tid] = nibAll;
    __syncthreads();

    // assemble packed words: thread -> (word slot w, plane b)
    {
        const int w = tid >> 3, b = tid & 7;
        unsigned int word = 0u;
        #pragma unroll
        for (int k = 0; k < 8; ++k)
            word |= ((nib[w * 8 + k] >> (b * 4)) & 0xFu) << (k * 4);
        bp[((size_t)blockIdx.x * 32 + w) * 8 + b] = word;
    }

    // block-reduce dice partials
    #pragma unroll
    for (int off = 32; off > 0; off >>= 1) {
        sp += __shfl_down(sp, off);
        st += __shfl_down(st, off);
        si += __shfl_down(si, off);
    }
    const int wave = tid >> 6, lane = tid & 63;
    if (lane == 0) { red[wave][0] = sp; red[wave][1] = st; red[wave][2] = si; }
    __syncthreads();
    if (tid == 0) {
        float a0 = 0.f, a1 = 0.f, a2 = 0.f;
        #pragma unroll
        for (int w = 0; w < 4; ++w) { a0 += red[w][0]; a1 += red[w][1]; a2 += red[w][2]; }
        part1[blockIdx.x] = make_float4(a0, a1, a2, 0.f);
    }
}

// ---- K2: bit stencil (v then h) + cnt*F partials (no atomics, no fences) ----
__global__ __launch_bounds__(256) void ba_k2(
    const unsigned int* __restrict__ bp, const float* __restrict__ Farr,
    float* __restrict__ part2)
{
    __shared__ unsigned int bdsh[256];
    __shared__ float red[4];
    const int tid = threadIdx.x;
    const int idx = blockIdx.x * 256 + tid;        // = wp*8 + b
    const int b   = idx & 7;
    const int wp  = idx >> 3;                      // word position, 0..9247
    const int y   = wp / WPR, xu = wp - y * WPR;

    // vertical 15-tap (clamped rows) on raw words, for xu-1, xu, xu+1
    unsigned int vorL = 0u, vanL = 0xFFFFFFFFu;
    unsigned int vorC = 0u, vanC = 0xFFFFFFFFu;
    unsigned int vorR = 0u, vanR = 0xFFFFFFFFu;
    #pragma unroll
    for (int j = 0; j < KK; ++j) {
        int yy = y - PADR + j; yy = yy < 0 ? 0 : (yy > HH - 1 ? HH - 1 : yy);
        int rb = (yy * WPR + xu) * 8 + b;
        unsigned int wc = bp[rb];
        vorC |= wc; vanC &= wc;
        if (xu > 0)       { unsigned int wl = bp[rb - 8];  vorL |= wl; vanL &= wl; }
        if (xu < WPR - 1) { unsigned int wr = bp[rb + 8];  vorR |= wr; vanR &= wr; }
    }
    if (xu == 0)       { vorL = 0u; vanL = 0xFFFFFFFFu; }   // clipped window edges
    if (xu == WPR - 1) { vorR = 0u; vanR = 0xFFFFFFFFu; }

    // horizontal 15-tap via u64 shift chains
    unsigned long long Ao = ((unsigned long long)vorC << 32) | vorL;
    unsigned long long Bo = ((unsigned long long)vorR << 32) | vorC;
    unsigned long long Aa = ((unsigned long long)vanC << 32) | vanL;
    unsigned long long Ba = ((unsigned long long)vanR << 32) | vanC;
    unsigned int hOR = vorC, hAND = vanC;
    #pragma unroll
    for (int s = 1; s <= PADR; ++s) {
        hOR  |= (unsigned int)(Ao >> (32 - s)) | (unsigned int)(Bo >> s);
        hAND &= (unsigned int)(Aa >> (32 - s)) & (unsigned int)(Ba >> s);
    }
    bdsh[tid] = hOR & ~hAND;                       // boundary bits, 32 px
    __syncthreads();

    // cnt*F: thread handles 4 px of word slot (tid>>3), group (tid&7)
    const int wslot = tid >> 3, sub = tid & 7;
    const int gpx = (blockIdx.x * 32 + wslot) * 32 + sub * 4;
    const float4 Fv = *(const float4*)(Farr + gpx);
    unsigned int w0 = bdsh[wslot * 8 + 0], w1 = bdsh[wslot * 8 + 1];
    unsigned int w2 = bdsh[wslot * 8 + 2], w3 = bdsh[wslot * 8 + 3];
    unsigned int w4 = bdsh[wslot * 8 + 4], w5 = bdsh[wslot * 8 + 5];
    unsigned int w6 = bdsh[wslot * 8 + 6], w7 = bdsh[wslot * 8 + 7];
    float bs = 0.f;
    const float* Fp = (const float*)&Fv;
    #pragma unroll
    for (int k = 0; k < 4; ++k) {
        int p = sub * 4 + k;
        unsigned int cnt = ((w0 >> p) & 1u) + ((w1 >> p) & 1u)
                         + ((w2 >> p) & 1u) + ((w3 >> p) & 1u)
                         + ((w4 >> p) & 1u) + ((w5 >> p) & 1u)
                         + ((w6 >> p) & 1u) + ((w7 >> p) & 1u);
        bs += (float)cnt * Fp[k];
    }

    #pragma unroll
    for (int off = 32; off > 0; off >>= 1) bs += __shfl_down(bs, off);
    int wave = tid >> 6, lane = tid & 63;
    if (lane == 0) red[wave] = bs;
    __syncthreads();
    if (tid == 0)
        part2[blockIdx.x] = red[0] + red[1] + red[2] + red[3];
}

// ---- final: sum partials, compose loss ----
__global__ __launch_bounds__(256) void ba_final(
    const float4* __restrict__ part1, const float* __restrict__ part2,
    float* __restrict__ out)
{
    __shared__ float red[4][4];
    float sp = 0.f, st = 0.f, si = 0.f, bs = 0.f;
    for (int i = threadIdx.x; i < NB1; i += 256) {
        float4 v = part1[i];
        sp += v.x; st += v.y; si += v.z;
    }
    for (int i = threadIdx.x; i < NB2; i += 256) bs += part2[i];
    #pragma unroll
    for (int off = 32; off > 0; off >>= 1) {
        sp += __shfl_down(sp, off);
        st += __shfl_down(st, off);
        si += __shfl_down(si, off);
        bs += __shfl_down(bs, off);
    }
    int wave = threadIdx.x >> 6, lane = threadIdx.x & 63;
    if (lane == 0) {
        red[wave][0] = sp; red[wave][1] = st; red[wave][2] = si; red[wave][3] = bs;
    }
    __syncthreads();
    if (threadIdx.x == 0) {
        float a0 = 0.f, a1 = 0.f, a2 = 0.f, a3 = 0.f;
        #pragma unroll
        for (int w = 0; w < 4; ++w) {
            a0 += red[w][0]; a1 += red[w][1]; a2 += red[w][2]; a3 += red[w][3];
        }
        float dice = 1.f - (2.f * a2 + 1.f) / (a0 + a1 + 1.f);
        float bce  = -a3 / (float)((long long)BB * BB * HH * WW);
        out[0] = dice + bce;
    }
}

extern "C" void kernel_launch(void* const* d_in, const int* in_sizes, int n_in,
                              void* d_out, int out_size, void* d_ws, size_t ws_size,
                              hipStream_t stream) {
    const float* pred = (const float*)d_in[0];
    const float* targ = (const float*)d_in[1];
    float* out = (float*)d_out;

    char* w = (char*)d_ws;
    unsigned int* bp    = (unsigned int*)w;                       // 295936 B
    float4*       Farr  = (float4*)(w + 295936);                  // 1183744 B
    float4*       part1 = (float4*)(w + 295936 + 1183744);        // 4624 B
    float*        part2 = (float*)(w + 295936 + 1183744 + 4624);  // 1156 B

    ba_k1<<<NB1, 256, 0, stream>>>(pred, targ, bp, Farr, part1);
    ba_k2<<<NB2, 256, 0, stream>>>(bp, (const float*)Farr, part2);
    ba_final<<<1, 256, 0, stream>>>(part1, part2, out);
}